// Round 2
// baseline (195.760 us; speedup 1.0000x reference)
//
#include <hip/hip_runtime.h>

// LinearTextEmbedding: out[o] = (|bits[o & 4095]| > 0.5) ? 1 : 0 for the whole
// 48x1024x1024 float32 output (channel stride & image size are multiples of 4096).
//
// Write-bandwidth bound: 201.3 MB stores, 16 KB reads.
//
// R0 lesson: one float4/thread over 49152 blocks ran at 1.08 TB/s — per-block
// overhead dominated. Now: fixed grid (2048 blocks = 8/CU, 32 waves/CU),
// grid-stride with 24 unrolled stores/thread. Total threads (524288) is a
// multiple of 1024, so each thread's bits float4 index (t & 1023) is invariant
// across iterations -> load once, store 24x.

#define N4       12582912u            // 48*1024*1024 / 4 float4 elements
#define NBLK     2048u
#define NTHR     (NBLK * 256u)        // 524288, multiple of 1024
#define NITER    (N4 / NTHR)          // 24, exact

__global__ __launch_bounds__(256) void
LinearTextEmbedding_57604101374655_kernel(const float4* __restrict__ bits4,
                                          float4* __restrict__ out) {
    unsigned t = blockIdx.x * 256u + threadIdx.x;
    float4 b = bits4[t & 1023u];      // 16 KB input, L1-resident
    float4 v;
    v.x = (fabsf(b.x) > 0.5f) ? 1.0f : 0.0f;
    v.y = (fabsf(b.y) > 0.5f) ? 1.0f : 0.0f;
    v.z = (fabsf(b.z) > 0.5f) ? 1.0f : 0.0f;
    v.w = (fabsf(b.w) > 0.5f) ? 1.0f : 0.0f;
    float4* p = out + t;
#pragma unroll
    for (unsigned i = 0; i < NITER; ++i) {
        *p = v;
        p += NTHR;
    }
}

extern "C" void kernel_launch(void* const* d_in, const int* in_sizes, int n_in,
                              void* d_out, int out_size, void* d_ws, size_t ws_size,
                              hipStream_t stream) {
    const float4* bits4 = (const float4*)d_in[0];
    float4* out = (float4*)d_out;
    LinearTextEmbedding_57604101374655_kernel<<<NBLK, 256, 0, stream>>>(bits4, out);
}